// Round 4
// baseline (2583.074 us; speedup 1.0000x reference)
//
#include <hip/hip_runtime.h>

#define W_  512
#define H_  512
#define HW  (512 * 512)      // 2^18
#define P_  20
#define B_  8
#define TL_ 29
#define IL_ 9

#define NB  1024             // blocks — exactly co-resident at <=128 VGPR (4/CU)
#define NT  256
#define TOT (NB * NT)        // 262144 threads
#define PPT (B_ * HW / TOT)  // 8 pixels per thread, strided by TOT (lanes stride-1)

// Whole 20-step advect scan in one persistent kernel.
// - Carry for step p>0 is evo_result[p-1] * 128 (pow2 scaling commutes exactly
//   with the lerp, so readback is bit-exact).
// - Grid barrier: device-scope atomic arrive + RMW spin. RMW (atomicAdd(cnt,0))
//   not a volatile load: per-XCD L2s are non-coherent, a cached load could spin
//   on a stale line. __threadfence() provides release/acquire (L2 wb/inv).
// - evo_result deliberately NOT __restrict__: it aliases the carry reads, and
//   the compiler must not hoist next-step gathers across the barrier.
__global__ __launch_bounds__(NT, 4) void fused_scan(
    const float* __restrict__ frames,     // (B, TL, H, W, 1)
    const float* __restrict__ motion,     // (B, 2P, H, W)
    const float* __restrict__ intensity,  // (B, P, H, W)
    float*                    evo_result, // (B, P, H, W)  written + re-read
    float* __restrict__       evo_motion, // (B, P, H, W)  write-only
    float* __restrict__       motion_out, // (B, 2P, H, W) write-only copy
    unsigned*                 barcnt)     // zeroed before launch
{
    const int tid = blockIdx.x * NT + threadIdx.x;

    for (int p = 0; p < P_; ++p) {
        const float scale = (p == 0) ? 1.0f : 128.0f;

        for (int j = 0; j < PPT; ++j) {
            const int px  = j * TOT + tid;     // lanes stride-1 over pixels
            const int b   = px >> 18;          // / HW
            const int rem = px & (HW - 1);
            const int y   = rem >> 9;
            const int x   = rem & (W_ - 1);

            const float* prev = (p == 0)
                ? frames + ((long)b * TL_ + (IL_ - 1)) * HW
                : evo_result + ((long)b * P_ + (p - 1)) * HW;

            const long mo0 = ((long)b * (2 * P_) + 2 * p) * HW + rem; // flow-x
            const long io  = ((long)b * P_ + p) * HW + rem;           // inten/out

            float f0 = motion[mo0];
            float f1 = motion[mo0 + HW];
            float iv = intensity[io];
            motion_out[mo0]      = f0;   // pure-copy output, from registers
            motion_out[mo0 + HW] = f1;

            float cx = fminf(fmaxf((float)x + f0, 0.0f), 511.0f);
            float cy = fminf(fmaxf((float)y + f1, 0.0f), 511.0f);

            float x0f = floorf(cx), y0f = floorf(cy);
            float wx = cx - x0f, wy = cy - y0f;
            int x0 = (int)x0f, y0 = (int)y0f;
            int x1 = min(x0 + 1, W_ - 1), y1 = min(y0 + 1, H_ - 1);

            const float* r0 = prev + y0 * W_;
            const float* r1 = prev + y1 * W_;
            float v00 = r0[x0], v01 = r0[x1];
            float v10 = r1[x0], v11 = r1[x1];
            float bil = scale * ((1.0f - wy) * ((1.0f - wx) * v00 + wx * v01)
                                       + wy  * ((1.0f - wx) * v10 + wx * v11));

            int xi = (int)rintf(cx);   // half-to-even == jnp.round
            int yi = (int)rintf(cy);
            float res = (scale * prev[yi * W_ + xi] + iv) * 0.0078125f; // /128 exact

            evo_result[io] = res;
            evo_motion[io] = bil;
        }

        if (p != P_ - 1) {             // grid barrier between steps
            __syncthreads();
            if (threadIdx.x == 0) {
                __threadfence();                       // release: flush writes
                atomicAdd(barcnt, 1u);
                const unsigned target = (unsigned)(p + 1) * NB;
                while (atomicAdd(barcnt, 0u) < target)
                    __builtin_amdgcn_s_sleep(8);
                __threadfence();                       // acquire: inv caches
            }
            __syncthreads();
        }
    }
}

extern "C" void kernel_launch(void* const* d_in, const int* in_sizes, int n_in,
                              void* d_out, int out_size, void* d_ws, size_t ws_size,
                              hipStream_t stream)
{
    const float* frames    = (const float*)d_in[0];
    const float* motion    = (const float*)d_in[1];
    const float* intensity = (const float*)d_in[2];

    float* out        = (float*)d_out;
    float* evo_result = out;                          // B*P*HW
    float* evo_motion = out + (long)B_ * P_ * HW;     // B*P*HW
    float* motion_out = out + 2L * B_ * P_ * HW;      // B*2P*HW
    unsigned* barcnt  = (unsigned*)d_ws;

    hipMemsetAsync(barcnt, 0, sizeof(unsigned), stream);   // reset barrier gen

    fused_scan<<<dim3(NB), dim3(NT), 0, stream>>>(
        frames, motion, intensity, evo_result, evo_motion, motion_out, barcnt);
}